// Round 7
// baseline (571.988 us; speedup 1.0000x reference)
//
#include <hip/hip_runtime.h>

#define T_SEQ 2048
#define BATCH 2
#define DMODEL 2048
#define NQH 32
#define NKVH 16
#define HD 128

typedef _Float16 f16;
typedef _Float16 f16x8 __attribute__((ext_vector_type(8)));
typedef _Float16 f16x4 __attribute__((ext_vector_type(4)));
typedef _Float16 f16x2 __attribute__((ext_vector_type(2)));
typedef float f32x4 __attribute__((ext_vector_type(4)));

typedef const __attribute__((address_space(1))) void* gptr_t;
typedef __attribute__((address_space(3))) void* sptr_t;
#define GLDS16(g, l) __builtin_amdgcn_global_load_lds((gptr_t)(g), (sptr_t)(l), 16, 0, 0)

// ---------------- merged transpose+convert: all four W -> f16 transposed ----
__global__ __launch_bounds__(256) void k_transpose_all(const float* __restrict__ Wq,
                                                       const float* __restrict__ Wk,
                                                       const float* __restrict__ Wv,
                                                       const float* __restrict__ Wo,
                                                       f16* __restrict__ WqkvT,
                                                       f16* __restrict__ WoT) {
  __shared__ float tile[32][33];
  const int z = blockIdx.z;
  const float* W;
  f16* WT;
  int N;
  if (z == 0)      { W = Wq; WT = WqkvT;                          N = 4096; }
  else if (z == 1) { W = Wk; WT = WqkvT + (size_t)4096 * 2048;    N = 2048; }
  else if (z == 2) { W = Wv; WT = WqkvT + (size_t)6144 * 2048;    N = 2048; }
  else             { W = Wo; WT = WoT;                            N = 2048; }
  const int K = 2048;
  int n0 = blockIdx.x * 32;
  if (n0 >= N) return;
  int k0 = blockIdx.y * 32;
  int tx = threadIdx.x & 31;
  int ty0 = threadIdx.x >> 5;
  #pragma unroll
  for (int i = 0; i < 4; ++i) {
    int ty = ty0 + i * 8;
    tile[ty][tx] = W[(size_t)(k0 + ty) * N + n0 + tx];
  }
  __syncthreads();
  #pragma unroll
  for (int i = 0; i < 4; ++i) {
    int ty = ty0 + i * 8;
    WT[(size_t)(n0 + ty) * K + k0 + tx] = (f16)tile[tx][ty];
  }
}

// ---------------- 4-phase-per-K-tile pipelined GEMM v4 (m201-style) ----------
// C(M,N) = A(M,K) @ B(K,N), B transposed (N,K). BK=64, 8 waves (WMxWN),
// double-buffered LDS (r5's proven swizzled layout). Per K-tile: 4 phases,
// each {stage 1/4 of next tile; ds_read quadrant; barrier; lgkm0; 16 MFMA;
// barrier}. Counted vmcnt(BH) at p1-end (certifies A-mh1 for p2) and
// vmcnt(AH) at p4-end (certifies B + A-mh0 for next p1). Never vmcnt(0)
// in the main loop. OM=0: f32 C. OM=3: fused QKV epilogue.
template<int BM, int BN, int WM, int WN, int OM>
__global__ __launch_bounds__(512, 2) void k_gemm4(const f16* __restrict__ A,
                                                  const f16* __restrict__ BT,
                                                  void* __restrict__ C0,
                                                  f16* __restrict__ Kh,
                                                  f16* __restrict__ VTg,
                                                  const float* __restrict__ cosb,
                                                  const float* __restrict__ sinb,
                                                  int M, int N, int K) {
  constexpr int MR = BM / WM / 16;
  constexpr int MR2 = MR / 2;
  constexpr int NR = BN / WN / 16;
  constexpr int ACH = BM / 64;           // A 16B-chunk batches (512-thread each)
  constexpr int BCH = BN / 64;
  constexpr int AH = ACH / 2;            // loads/thread per A-mh stage batch
  constexpr int BH = BCH / 2;            // loads/thread per B stage batch
  static_assert(ACH == 4, "A staging split assumes BM==256");
  __shared__ alignas(16) f16 Al[2][BM * 64];
  __shared__ alignas(16) f16 Bl[2][BN * 64];
  const int tid = threadIdx.x;
  const int lane = tid & 63;
  const int w = tid >> 6;
  const int wr = w / WN, wc = w % WN;
  const int lr = lane & 15, lg = lane >> 4;
  const int nbx = N / BN;
  const int cpx = gridDim.x >> 3;
  const int wg = (blockIdx.x & 7) * cpx + (blockIdx.x >> 3);
  const int m0 = (wg / nbx) * BM, n0 = (wg % nbx) * BN;

// stage B rows [half*BN/2, (half+1)*BN/2)
#define ST_B(HALF, BB, KK)                                                      \
  { _Pragma("unroll")                                                           \
    for (int q = (HALF) * BH; q < (HALF) * BH + BH; ++q) {                      \
      int idx = q * 512 + tid; int r = idx >> 3, g = idx & 7;                   \
      GLDS16(BT + (size_t)(n0 + r) * K + (KK) + ((g ^ (r & 7)) * 8),            \
             &Bl[BB][idx * 8]);                                                 \
    } }
// stage A rows for m-half PAR (even q batches = mh0 rows, odd = mh1 rows)
#define ST_A(PAR, BB, KK)                                                       \
  { _Pragma("unroll")                                                           \
    for (int i2 = 0; i2 < AH; ++i2) {                                           \
      int q = 2 * i2 + (PAR);                                                   \
      int idx = q * 512 + tid; int r = idx >> 3, g = idx & 7;                   \
      GLDS16(A + (size_t)(m0 + r) * K + (KK) + ((g ^ (r & 7)) * 8),             \
             &Al[BB][idx * 8]);                                                 \
    } }
#define LDA8(AF, BUF, MH, KH)                                                   \
  { _Pragma("unroll")                                                           \
    for (int i = 0; i < MR2; ++i) {                                             \
      int r = wr * (BM / WM) + ((MH) * MR2 + i) * 16 + lr;                      \
      AF[i] = *(const f16x8*)&Al[BUF][r * 64 + ((((KH) * 4 + lg) ^ (r & 7)) * 8)]; \
    } }
#define LDB8(BF, BUF, KH)                                                       \
  { _Pragma("unroll")                                                           \
    for (int j = 0; j < NR; ++j) {                                              \
      int r = wc * (BN / WN) + j * 16 + lr;                                     \
      BF[j] = *(const f16x8*)&Bl[BUF][r * 64 + ((((KH) * 4 + lg) ^ (r & 7)) * 8)]; \
    } }
#define FMA16(AF, BF, MH)                                                       \
  { __builtin_amdgcn_s_setprio(1);                                              \
    _Pragma("unroll")                                                           \
    for (int i = 0; i < MR2; ++i)                                               \
      _Pragma("unroll")                                                         \
      for (int j = 0; j < NR; ++j)                                              \
        acc[(MH) * MR2 + i][j] =                                                \
          __builtin_amdgcn_mfma_f32_16x16x32_f16(AF[i], BF[j], acc[(MH) * MR2 + i][j], 0, 0, 0); \
    __builtin_amdgcn_s_setprio(0); }
#define BAR() __builtin_amdgcn_s_barrier()
#define LGKM0() { asm volatile("s_waitcnt lgkmcnt(0)" ::: "memory");            \
                  __builtin_amdgcn_sched_barrier(0); }
#define VMW(N) asm volatile("s_waitcnt vmcnt(" #N ")" ::: "memory")
#define VM_BH() { if constexpr (BH == 2) VMW(2); else VMW(1); }
#define VM_AH() { VMW(2); }

  f32x4 acc[MR][NR] = {};
  // prologue: full tile 0 staged; certify B + A-mh0 (leave A-mh1 in flight)
  ST_B(0, 0, 0); ST_B(1, 0, 0); ST_A(0, 0, 0); ST_A(1, 0, 0);
  VM_AH();
  BAR();

  const int nt = K / 64;
  #pragma unroll 2
  for (int t = 0; t < nt; ++t) {
    const int buf = t & 1;
    const int kk1 = (t + 1) * 64;
    const bool nxt = (t + 1 < nt);
    f16x8 af[MR2], bf[NR];
    // ---- phase 1: quadrant (kh0, mh0); stage B12' ----
    if (nxt) ST_B(0, buf ^ 1, kk1);
    LDB8(bf, buf, 0);
    LDA8(af, buf, 0, 0);
    BAR();
    LGKM0();
    FMA16(af, bf, 0);
    if (nxt) { VM_BH(); } else { VMW(0); }   // certify A-mh1 (read in p2)
    BAR();
    // ---- phase 2: quadrant (kh0, mh1); stage B34' ----
    if (nxt) ST_B(1, buf ^ 1, kk1);
    LDA8(af, buf, 1, 0);
    BAR();
    LGKM0();
    FMA16(af, bf, 1);
    BAR();
    // ---- phase 3: quadrant (kh1, mh0); stage A-mh0' ----
    if (nxt) ST_A(0, buf ^ 1, kk1);
    LDB8(bf, buf, 1);
    LDA8(af, buf, 0, 1);
    BAR();
    LGKM0();
    FMA16(af, bf, 0);
    BAR();
    // ---- phase 4: quadrant (kh1, mh1); stage A-mh1' ----
    if (nxt) ST_A(1, buf ^ 1, kk1);
    LDA8(af, buf, 1, 1);
    BAR();
    LGKM0();
    FMA16(af, bf, 1);
    if (nxt) { VM_AH(); } else { VMW(0); }   // certify B' + A-mh0' for next p1
    BAR();
  }
#undef ST_B
#undef ST_A
#undef LDA8
#undef LDB8
#undef FMA16
#undef BAR
#undef LGKM0
#undef VMW
#undef VM_BH
#undef VM_AH

  // ---- epilogue ----
  const int mb = m0 + wr * (BM / WM);
  const int nb = n0 + wc * (BN / WN);
  if constexpr (OM == 0) {
    float* C = (float*)C0;
    #pragma unroll
    for (int i = 0; i < MR; ++i)
      #pragma unroll
      for (int j = 0; j < NR; ++j) {
        int r0 = mb + i * 16 + lg * 4;
        int c = nb + j * 16 + lr;
        #pragma unroll
        for (int r = 0; r < 4; ++r)
          C[(size_t)(r0 + r) * N + c] = acc[i][j][r];
      }
  } else {
    if (n0 < 6144) {  // Q (cols 0..4095) or K (4096..6143): RoPE, row-major f16
      f16* dst = (n0 < 4096) ? (f16*)C0 : Kh;
      const int ncols = (n0 < 4096) ? 4096 : 2048;
      const int coff = (n0 < 4096) ? 0 : 4096;
      #pragma unroll
      for (int i = 0; i < MR; ++i)
        #pragma unroll
        for (int j = 0; j < NR; ++j) {
          int c = nb + j * 16 + lr - coff;
          int jp = (c & 127) >> 1;
          bool odd = (c & 1);
          #pragma unroll
          for (int r = 0; r < 4; ++r) {
            int row = mb + i * 16 + lg * 4 + r;
            int t = row & (T_SEQ - 1);
            float v = acc[i][j][r];
            float pv = __shfl_xor(v, 1);   // partner column (c^1) value
            float cs = cosb[t * 64 + jp], sn = sinb[t * 64 + jp];
            float out = odd ? (pv * sn + v * cs) : (v * cs - pv * sn);
            dst[(size_t)row * ncols + c] = (f16)out;
          }
        }
    } else {          // V (cols 6144..8191): transposed per head VT[b][h][d][t]
      #pragma unroll
      for (int i = 0; i < MR; ++i)
        #pragma unroll
        for (int j = 0; j < NR; ++j) {
          int c = nb + j * 16 + lr - 6144;
          int head = c >> 7, d = c & 127;
          int row0 = mb + i * 16 + lg * 4;
          int bb = row0 >> 11, t0 = row0 & (T_SEQ - 1);
          f16x4 zv;
          #pragma unroll
          for (int r = 0; r < 4; ++r) zv[r] = (f16)acc[i][j][r];
          *(f16x4*)(VTg + ((size_t)(bb * NKVH + head) * HD + d) * T_SEQ + t0) = zv;
        }
    }
  }
}

// ---------------- lambda = sigmoid(x @ Wlam) + x->f16 convert (fused) -------
__global__ __launch_bounds__(256) void k_lambda_conv(const float* __restrict__ x,
                                                     const float* __restrict__ Wlam,
                                                     float* __restrict__ lam,
                                                     f16* __restrict__ xh) {
  int row = blockIdx.x;
  const float* xr = x + (size_t)row * DMODEL;
  const int e = threadIdx.x * 8;            // 256 threads x 8 = 2048
  const float4* xp = (const float4*)(xr + e);
  float4 a = xp[0], b2 = xp[1];
  float xv[8] = {a.x, a.y, a.z, a.w, b2.x, b2.y, b2.z, b2.w};
  f16x8 hv;
  #pragma unroll
  for (int j = 0; j < 8; ++j) hv[j] = (f16)xv[j];
  *(f16x8*)(xh + (size_t)row * DMODEL + e) = hv;
  float acc[16];
  #pragma unroll
  for (int h = 0; h < 16; ++h) acc[h] = 0.f;
  #pragma unroll
  for (int j = 0; j < 8; ++j) {
    const float4* wp = (const float4*)(Wlam + (size_t)(e + j) * 16);
    #pragma unroll
    for (int g = 0; g < 4; ++g) {
      float4 wv = wp[g];
      acc[g * 4 + 0] += xv[j] * wv.x; acc[g * 4 + 1] += xv[j] * wv.y;
      acc[g * 4 + 2] += xv[j] * wv.z; acc[g * 4 + 3] += xv[j] * wv.w;
    }
  }
  #pragma unroll
  for (int h = 0; h < 16; ++h)
    for (int off = 32; off > 0; off >>= 1)
      acc[h] += __shfl_down(acc[h], off);
  __shared__ float part[4][16];
  int lane = threadIdx.x & 63, w = threadIdx.x >> 6;
  if (lane == 0) {
    #pragma unroll
    for (int h = 0; h < 16; ++h) part[w][h] = acc[h];
  }
  __syncthreads();
  if (threadIdx.x < 16) {
    float s = part[0][threadIdx.x] + part[1][threadIdx.x] + part[2][threadIdx.x] + part[3][threadIdx.x];
    lam[row * 16 + threadIdx.x] = 1.f / (1.f + __expf(-s));
  }
}

// ---------------- causal flash attention v4 + setprio ------------------------
__global__ __launch_bounds__(256, 4) void k_attn4(const f16* __restrict__ Q,
                                                  const f16* __restrict__ K,
                                                  const f16* __restrict__ VT,
                                                  f16* __restrict__ O) {
  __shared__ f16 Kl[64 * 128];
  __shared__ f16 Vl[128 * 64];
  __shared__ f16 Pl[4][16][40];
  const int tid = threadIdx.x;
  const int lane = tid & 63;
  const int w = tid >> 6;
  const int lr = lane & 15, lg = lane >> 4;
  const int flat = blockIdx.x;
  const int xcd = flat & 7;
  const int work = xcd * 128 + (flat >> 3);
  const int grp = work >> 5;
  const int within = work & 31;
  const int b = grp >> 4, hkv = grp & 15;
  const int h = hkv * 2 + (within >> 4);
  const int bx = within & 15;
  const f16* Kg  = K  + (size_t)b * T_SEQ * (NKVH * HD) + hkv * HD;
  const f16* VTg = VT + (size_t)(b * NKVH + hkv) * HD * T_SEQ;
  const float sc = 0.08838834764831845f;

  #pragma unroll 1
  for (int half = 0; half < 2; ++half) {
    const int qt = half ? (31 - bx) : bx;
    const int qb = qt * 64;
    const int qw = qb + w * 16;
    const int qrow = qw + lr;
    f16x8 qf[4];
    {
      const f16* qp = Q + (size_t)(b * T_SEQ + qrow) * (NQH * HD) + h * HD + lg * 8;
      #pragma unroll
      for (int c = 0; c < 4; ++c) qf[c] = *(const f16x8*)(qp + c * 32);
    }
    f32x4 o[8] = {};
    float mi = -1e30f, li = 0.f;

    const int nt = qt + 1;
    #pragma unroll 1
    for (int t = 0; t < nt; ++t) {
      const int s0 = t * 64;
      #pragma unroll
      for (int qq = 0; qq < 4; ++qq) {
        int idx = qq * 256 + tid;
        int r = idx >> 4, g = idx & 15;
        GLDS16(Kg + (size_t)(s0 + r) * (NKVH * HD) + (g ^ (r & 7)) * 8, &Kl[idx * 8]);
      }
      #pragma unroll
      for (int qq = 0; qq < 4; ++qq) {
        int idx = qq * 256 + tid;
        int d = idx >> 3, g = idx & 7;
        GLDS16(VTg + (size_t)d * T_SEQ + s0 + (g ^ (d & 7)) * 8, &Vl[idx * 8]);
      }
      __syncthreads();

      f32x4 sf[4] = {};
      __builtin_amdgcn_s_setprio(1);
      #pragma unroll
      for (int c = 0; c < 4; ++c) {
        #pragma unroll
        for (int nb = 0; nb < 4; ++nb) {
          f16x8 kf = *(const f16x8*)&Kl[(((nb * 16 + lr) * 16) + ((c * 4 + lg) ^ (lr & 7))) * 8];
          sf[nb] = __builtin_amdgcn_mfma_f32_16x16x32_f16(kf, qf[c], sf[nb], 0, 0, 0);
        }
      }
      __builtin_amdgcn_s_setprio(0);
      float v[16];
      #pragma unroll
      for (int nb = 0; nb < 4; ++nb)
        #pragma unroll
        for (int rr = 0; rr < 4; ++rr) {
          float x = sf[nb][rr] * sc;
          int kv = s0 + nb * 16 + lg * 4 + rr;
          v[nb * 4 + rr] = (kv > qrow) ? -1e30f : x;
        }
      float pm = v[0];
      #pragma unroll
      for (int i = 1; i < 16; ++i) pm = fmaxf(pm, v[i]);
      pm = fmaxf(pm, __shfl_xor(pm, 16));
      pm = fmaxf(pm, __shfl_xor(pm, 32));
      float mnew = fmaxf(mi, pm);
      float a = __expf(mi - mnew);
      mi = mnew;
      float rs = 0.f;
      #pragma unroll
      for (int i = 0; i < 16; ++i) { float p = __expf(v[i] - mnew); v[i] = p; rs += p; }
      rs += __shfl_xor(rs, 16);
      rs += __shfl_xor(rs, 32);
      li = a * li + rs;
      float ab[4];
      #pragma unroll
      for (int rr = 0; rr < 4; ++rr) ab[rr] = __shfl(a, lg * 4 + rr);
      #pragma unroll
      for (int j = 0; j < 8; ++j)
        #pragma unroll
        for (int rr = 0; rr < 4; ++rr) o[j][rr] *= ab[rr];
      #pragma unroll
      for (int ks = 0; ks < 2; ++ks) {
        #pragma unroll
        for (int nb2 = 0; nb2 < 2; ++nb2) {
          int nb = ks * 2 + nb2;
          f16x4 pk;
          #pragma unroll
          for (int rr = 0; rr < 4; ++rr) pk[rr] = (f16)v[nb * 4 + rr];
          *(f16x4*)&Pl[w][lr][nb2 * 16 + lg * 4] = pk;
        }
        f16x8 pa = *(const f16x8*)&Pl[w][lr][lg * 8];
        __builtin_amdgcn_s_setprio(1);
        #pragma unroll
        for (int j = 0; j < 8; ++j) {
          f16x8 vbj = *(const f16x8*)&Vl[(((j * 16 + lr) * 8) + ((ks * 4 + lg) ^ (lr & 7))) * 8];
          o[j] = __builtin_amdgcn_mfma_f32_16x16x32_f16(pa, vbj, o[j], 0, 0, 0);
        }
        __builtin_amdgcn_s_setprio(0);
      }
      __syncthreads();
    }
    float lib[4];
    #pragma unroll
    for (int rr = 0; rr < 4; ++rr) lib[rr] = 1.f / __shfl(li, lg * 4 + rr);
    #pragma unroll
    for (int j = 0; j < 8; ++j)
      #pragma unroll
      for (int rr = 0; rr < 4; ++rr) {
        float vv = o[j][rr] * lib[rr];
        O[(size_t)(b * T_SEQ + qw + lg * 4 + rr) * (NQH * HD) + h * HD + j * 16 + lr] = (f16)vv;
      }
  }
}

// ---------------- differential combine: Z = attn_even - lam * attn_odd ------
__global__ void k_combine(const f16* __restrict__ attn, const float* __restrict__ lam,
                          f16* __restrict__ Z) {
  int idx = blockIdx.x * blockDim.x + threadIdx.x;
  int d4 = idx & 31;
  int tmp = idx >> 5;
  int h = tmp & 15;
  int row = tmp >> 4;
  if (row >= BATCH * T_SEQ) return;
  float lv = lam[row * 16 + h];
  f16x4 a1 = *(const f16x4*)(attn + (size_t)row * 4096 + (2 * h) * 128 + d4 * 4);
  f16x4 a2 = *(const f16x4*)(attn + (size_t)row * 4096 + (2 * h + 1) * 128 + d4 * 4);
  f16x4 z;
  #pragma unroll
  for (int e = 0; e < 4; ++e) z[e] = (f16)((float)a1[e] - lv * (float)a2[e]);
  *(f16x4*)(Z + (size_t)row * 2048 + h * 128 + d4 * 4) = z;
}

extern "C" void kernel_launch(void* const* d_in, const int* in_sizes, int n_in,
                              void* d_out, int out_size, void* d_ws, size_t ws_size,
                              hipStream_t stream) {
  const float* x    = (const float*)d_in[0];
  const float* cosb = (const float*)d_in[1];
  const float* sinb = (const float*)d_in[2];
  const float* Wq   = (const float*)d_in[3];
  const float* Wk   = (const float*)d_in[4];
  const float* Wv   = (const float*)d_in[5];
  const float* Wo   = (const float*)d_in[6];
  const float* Wlam = (const float*)d_in[7];

  char* ws = (char*)d_ws;
  f16*  xh     = (f16*)(ws);                      // 16 MB  x in f16
  f16*  WqkvT  = (f16*)(ws + 16777216);           // 32 MB  [Wq^T; Wk^T; Wv^T] (8192,2048)
  f16*  WoT    = (f16*)(ws + 50331648);           //  8 MB
  f16*  Qh     = (f16*)(ws + 58720256);           // 32 MB  (4096,4096) rope'd
  f16*  Kh     = (f16*)(ws + 92274688);           // 16 MB  (4096,2048) rope'd
  f16*  VTg    = (f16*)(ws + 109051904);          // 16 MB  (32 head-slices,128,2048)
  f16*  At     = (f16*)(ws + 125829120);          // 32 MB  attn out (4096,4096)
  f16*  Zh     = (f16*)(ws + 159383552);          // 16 MB  (4096,2048)
  float* lam   = (float*)(ws + 176160768);        // 256 KB (4096,16)

  k_transpose_all<<<dim3(128, 64, 4), 256, 0, stream>>>(Wq, Wk, Wv, Wo, WqkvT, WoT);
  k_lambda_conv<<<4096, 256, 0, stream>>>(x, Wlam, lam, xh);

  // fused QKV projection + RoPE + V-transpose: M=4096, N=8192, K=2048
  k_gemm4<256, 256, 2, 4, 3><<<512, 512, 0, stream>>>(xh, WqkvT, Qh, Kh, VTg,
                                                      cosb, sinb, 4096, 8192, 2048);

  k_attn4<<<1024, 256, 0, stream>>>(Qh, Kh, VTg, At);

  k_combine<<<(BATCH * T_SEQ * 16 * 32) / 256, 256, 0, stream>>>(At, lam, Zh);

  // output projection: M=4096, N=2048, K=2048 -> f32 d_out
  k_gemm4<256, 128, 2, 4, 0><<<256, 512, 0, stream>>>(Zh, WoT, d_out, nullptr, nullptr,
                                                      nullptr, nullptr, 4096, 2048, 2048);
}

// Round 8
// 439.763 us; speedup vs baseline: 1.3007x; 1.3007x over previous
//
#include <hip/hip_runtime.h>

#define T_SEQ 2048
#define BATCH 2
#define DMODEL 2048
#define NQH 32
#define NKVH 16
#define HD 128

typedef _Float16 f16;
typedef _Float16 f16x8 __attribute__((ext_vector_type(8)));
typedef _Float16 f16x4 __attribute__((ext_vector_type(4)));
typedef _Float16 f16x2 __attribute__((ext_vector_type(2)));
typedef float f32x4 __attribute__((ext_vector_type(4)));

typedef const __attribute__((address_space(1))) void* gptr_t;
typedef __attribute__((address_space(3))) void* sptr_t;
#define GLDS16(g, l) __builtin_amdgcn_global_load_lds((gptr_t)(g), (sptr_t)(l), 16, 0, 0)

// ---------------- merged transpose+convert: all four W -> f16 transposed ----
__global__ __launch_bounds__(256) void k_transpose_all(const float* __restrict__ Wq,
                                                       const float* __restrict__ Wk,
                                                       const float* __restrict__ Wv,
                                                       const float* __restrict__ Wo,
                                                       f16* __restrict__ WqkvT,
                                                       f16* __restrict__ WoT) {
  __shared__ float tile[32][33];
  const int z = blockIdx.z;
  const float* W;
  f16* WT;
  int N;
  if (z == 0)      { W = Wq; WT = WqkvT;                          N = 4096; }
  else if (z == 1) { W = Wk; WT = WqkvT + (size_t)4096 * 2048;    N = 2048; }
  else if (z == 2) { W = Wv; WT = WqkvT + (size_t)6144 * 2048;    N = 2048; }
  else             { W = Wo; WT = WoT;                            N = 2048; }
  const int K = 2048;
  int n0 = blockIdx.x * 32;
  if (n0 >= N) return;
  int k0 = blockIdx.y * 32;
  int tx = threadIdx.x & 31;
  int ty0 = threadIdx.x >> 5;
  #pragma unroll
  for (int i = 0; i < 4; ++i) {
    int ty = ty0 + i * 8;
    tile[ty][tx] = W[(size_t)(k0 + ty) * N + n0 + tx];
  }
  __syncthreads();
  #pragma unroll
  for (int i = 0; i < 4; ++i) {
    int ty = ty0 + i * 8;
    WT[(size_t)(n0 + ty) * K + k0 + tx] = (f16)tile[tx][ty];
  }
}

// ---------------- pipelined GEMM v2 (round-5 proven structure) ---------------
// C(M,N) = A(M,K) @ B(K,N), B given transposed (N,K). BK=64, 8 waves (WMxWN),
// double-buffered LDS, counted vmcnt (prefetch spans barriers), 2 barriers/tile.
// OM=0: f32 C.  OM=3: fused QKV epilogue (RoPE for Q/K, transposed store for V).
template<int BM, int BN, int WM, int WN, int OM>
__global__ __launch_bounds__(512, 2) void k_gemm2(const f16* __restrict__ A,
                                                  const f16* __restrict__ BT,
                                                  void* __restrict__ C0,
                                                  f16* __restrict__ Kh,
                                                  f16* __restrict__ VTg,
                                                  const float* __restrict__ cosb,
                                                  const float* __restrict__ sinb,
                                                  int M, int N, int K) {
  constexpr int MR = BM / WM / 16;
  constexpr int NR = BN / WN / 16;
  constexpr int ACH = BM / 64;
  constexpr int BCH = BN / 64;
  __shared__ alignas(16) f16 Al[2][BM * 64];
  __shared__ alignas(16) f16 Bl[2][BN * 64];
  const int tid = threadIdx.x;
  const int lane = tid & 63;
  const int w = tid >> 6;
  const int wr = w / WN, wc = w % WN;
  const int lr = lane & 15, lg = lane >> 4;
  const int nbx = N / BN;
  const int cpx = gridDim.x >> 3;
  const int wg = (blockIdx.x & 7) * cpx + (blockIdx.x >> 3);
  const int m0 = (wg / nbx) * BM, n0 = (wg % nbx) * BN;

  auto STAGE = [&](int buf, int kk) {
    #pragma unroll
    for (int q = 0; q < ACH; ++q) {
      int idx = q * 512 + tid;
      int r = idx >> 3, g = idx & 7;
      GLDS16(A + (size_t)(m0 + r) * K + kk + ((g ^ (r & 7)) * 8), &Al[buf][idx * 8]);
    }
    #pragma unroll
    for (int q = 0; q < BCH; ++q) {
      int idx = q * 512 + tid;
      int r = idx >> 3, g = idx & 7;
      GLDS16(BT + (size_t)(n0 + r) * K + kk + ((g ^ (r & 7)) * 8), &Bl[buf][idx * 8]);
    }
  };

  f32x4 acc[MR][NR] = {};
  STAGE(0, 0);
  const int nt = K / 64;
  #pragma unroll 2
  for (int t = 0; t < nt; ++t) {
    const int buf = t & 1;
    if (t + 1 < nt) {
      STAGE(buf ^ 1, (t + 1) * 64);
      __builtin_amdgcn_sched_barrier(0);
      if constexpr (ACH + BCH == 8) asm volatile("s_waitcnt vmcnt(8)" ::: "memory");
      else                          asm volatile("s_waitcnt vmcnt(6)" ::: "memory");
    } else {
      __builtin_amdgcn_sched_barrier(0);
      asm volatile("s_waitcnt vmcnt(0)" ::: "memory");
    }
    __builtin_amdgcn_s_barrier();          // current tile visible to all waves
    __builtin_amdgcn_sched_barrier(0);
    #pragma unroll
    for (int kh = 0; kh < 2; ++kh) {
      f16x8 af[MR], bf[NR];
      #pragma unroll
      for (int i = 0; i < MR; ++i) {
        int r = wr * (BM / WM) + i * 16 + lr;
        af[i] = *(const f16x8*)&Al[buf][r * 64 + (((kh * 4 + lg) ^ (r & 7)) * 8)];
      }
      #pragma unroll
      for (int j = 0; j < NR; ++j) {
        int r = wc * (BN / WN) + j * 16 + lr;
        bf[j] = *(const f16x8*)&Bl[buf][r * 64 + (((kh * 4 + lg) ^ (r & 7)) * 8)];
      }
      #pragma unroll
      for (int i = 0; i < MR; ++i)
        #pragma unroll
        for (int j = 0; j < NR; ++j)
          acc[i][j] = __builtin_amdgcn_mfma_f32_16x16x32_f16(af[i], bf[j], acc[i][j], 0, 0, 0);
    }
    __builtin_amdgcn_sched_barrier(0);
    __builtin_amdgcn_s_barrier();          // all waves done reading buf
    __builtin_amdgcn_sched_barrier(0);
  }

  // ---- epilogue ----
  const int mb = m0 + wr * (BM / WM);
  const int nb = n0 + wc * (BN / WN);
  if constexpr (OM == 0) {
    float* C = (float*)C0;
    #pragma unroll
    for (int i = 0; i < MR; ++i)
      #pragma unroll
      for (int j = 0; j < NR; ++j) {
        int r0 = mb + i * 16 + lg * 4;
        int c = nb + j * 16 + lr;
        #pragma unroll
        for (int r = 0; r < 4; ++r)
          C[(size_t)(r0 + r) * N + c] = acc[i][j][r];
      }
  } else {
    if (n0 < 6144) {  // Q (cols 0..4095) or K (4096..6143): RoPE, row-major f16
      f16* dst = (n0 < 4096) ? (f16*)C0 : Kh;
      const int ncols = (n0 < 4096) ? 4096 : 2048;
      const int coff = (n0 < 4096) ? 0 : 4096;
      #pragma unroll
      for (int i = 0; i < MR; ++i)
        #pragma unroll
        for (int j = 0; j < NR; ++j) {
          int c = nb + j * 16 + lr - coff;
          int jp = (c & 127) >> 1;
          bool odd = (c & 1);
          #pragma unroll
          for (int r = 0; r < 4; ++r) {
            int row = mb + i * 16 + lg * 4 + r;
            int t = row & (T_SEQ - 1);
            float v = acc[i][j][r];
            float pv = __shfl_xor(v, 1);   // partner column (c^1) value
            float cs = cosb[t * 64 + jp], sn = sinb[t * 64 + jp];
            float out = odd ? (pv * sn + v * cs) : (v * cs - pv * sn);
            dst[(size_t)row * ncols + c] = (f16)out;
          }
        }
    } else {          // V (cols 6144..8191): transposed per head VT[b][h][d][t]
      #pragma unroll
      for (int i = 0; i < MR; ++i)
        #pragma unroll
        for (int j = 0; j < NR; ++j) {
          int c = nb + j * 16 + lr - 6144;
          int head = c >> 7, d = c & 127;
          int row0 = mb + i * 16 + lg * 4;
          int bb = row0 >> 11, t0 = row0 & (T_SEQ - 1);
          f16x4 zv;
          #pragma unroll
          for (int r = 0; r < 4; ++r) zv[r] = (f16)acc[i][j][r];
          *(f16x4*)(VTg + ((size_t)(bb * NKVH + head) * HD + d) * T_SEQ + t0) = zv;
        }
    }
  }
}

// ---------------- lambda = sigmoid(x @ Wlam) + x->f16 convert (fused) -------
__global__ __launch_bounds__(256) void k_lambda_conv(const float* __restrict__ x,
                                                     const float* __restrict__ Wlam,
                                                     float* __restrict__ lam,
                                                     f16* __restrict__ xh) {
  int row = blockIdx.x;
  const float* xr = x + (size_t)row * DMODEL;
  const int e = threadIdx.x * 8;
  const float4* xp = (const float4*)(xr + e);
  float4 a = xp[0], b2 = xp[1];
  float xv[8] = {a.x, a.y, a.z, a.w, b2.x, b2.y, b2.z, b2.w};
  f16x8 hv;
  #pragma unroll
  for (int j = 0; j < 8; ++j) hv[j] = (f16)xv[j];
  *(f16x8*)(xh + (size_t)row * DMODEL + e) = hv;
  float acc[16];
  #pragma unroll
  for (int h = 0; h < 16; ++h) acc[h] = 0.f;
  #pragma unroll
  for (int j = 0; j < 8; ++j) {
    const float4* wp = (const float4*)(Wlam + (size_t)(e + j) * 16);
    #pragma unroll
    for (int g = 0; g < 4; ++g) {
      float4 wv = wp[g];
      acc[g * 4 + 0] += xv[j] * wv.x; acc[g * 4 + 1] += xv[j] * wv.y;
      acc[g * 4 + 2] += xv[j] * wv.z; acc[g * 4 + 3] += xv[j] * wv.w;
    }
  }
  #pragma unroll
  for (int h = 0; h < 16; ++h)
    for (int off = 32; off > 0; off >>= 1)
      acc[h] += __shfl_down(acc[h], off);
  __shared__ float part[4][16];
  int lane = threadIdx.x & 63, w = threadIdx.x >> 6;
  if (lane == 0) {
    #pragma unroll
    for (int h = 0; h < 16; ++h) part[w][h] = acc[h];
  }
  __syncthreads();
  if (threadIdx.x < 16) {
    float s = part[0][threadIdx.x] + part[1][threadIdx.x] + part[2][threadIdx.x] + part[3][threadIdx.x];
    lam[row * 16 + threadIdx.x] = 1.f / (1.f + __expf(-s));
  }
}

// ---------------- causal flash attention v5 ---------------------------------
// 512 threads (8 waves): waves 0-3 -> q-head 2*hkv, waves 4-7 -> 2*hkv+1.
// K/V staged ONCE per kv-head pair. KV tile 64 single-buffered LDS, but next
// tile prefetched into REGISTERS during compute (T14) and ds_written after the
// barrier. Swapped QK^T in-register softmax + defer-max THR=8 (T13).
// LDS 42 KB, VGPR <=128 -> 2 blocks/CU = 16 waves/CU.
__global__ __launch_bounds__(512, 4) void k_attn5(const f16* __restrict__ Q,
                                                  const f16* __restrict__ K,
                                                  const f16* __restrict__ VT,
                                                  f16* __restrict__ O) {
  __shared__ f16 Kl[64 * 128];     // 16 KB, swizzled slots
  __shared__ f16 Vl[128 * 64];     // 16 KB, swizzled slots
  __shared__ f16 Pl[8][16][40];    // 10 KB, per-wave P half-tile
  const int tid = threadIdx.x;
  const int lane = tid & 63;
  const int w = tid >> 6;          // 0..7
  const int lr = lane & 15, lg = lane >> 4;
  // ---- XCD-pinned decode: 512 blocks = 32 (b,hkv) groups x 16 qtile-pairs --
  const int flat = blockIdx.x;
  const int xcd = flat & 7;
  const int work = xcd * 64 + (flat >> 3);
  const int grp = work >> 4;           // b*16 + hkv
  const int bx = work & 15;
  const int b = grp >> 4, hkv = grp & 15;
  const int h = hkv * 2 + (w >> 2);    // wave's q-head
  const int wq = w & 3;                // wave's 16-row slice
  const int kvstride = NKVH * HD;
  const f16* Kg  = K  + (size_t)b * T_SEQ * kvstride + hkv * HD;
  const f16* VTg = VT + (size_t)(b * NKVH + hkv) * HD * T_SEQ;
  const float sc = 0.08838834764831845f;  // 1/sqrt(128)

  #pragma unroll 1
  for (int half = 0; half < 2; ++half) {
    const int qt = half ? (31 - bx) : bx;
    const int qb = qt * 64;
    const int qw = qb + wq * 16;
    const int qrow = qw + lr;
    f16x8 qf[4];
    {
      const f16* qp = Q + (size_t)(b * T_SEQ + qrow) * (NQH * HD) + h * HD + lg * 8;
      #pragma unroll
      for (int c = 0; c < 4; ++c) qf[c] = *(const f16x8*)(qp + c * 32);
    }
    f32x4 o[8] = {};
    float mi = -1e30f, li = 0.f;

    const int nt = qt + 1;
    // ---- blocking stage of tile 0 (GLDS direct, pre-swizzled source) ----
    #pragma unroll
    for (int q = 0; q < 2; ++q) {
      int idx = q * 512 + tid;
      int r = idx >> 4, g = idx & 15;
      GLDS16(Kg + (size_t)r * kvstride + (g ^ (r & 7)) * 8, &Kl[idx * 8]);
    }
    #pragma unroll
    for (int q = 0; q < 2; ++q) {
      int idx = q * 512 + tid;
      int d = idx >> 3, g = idx & 7;
      GLDS16(VTg + (size_t)d * T_SEQ + (g ^ (d & 7)) * 8, &Vl[idx * 8]);
    }
    __syncthreads();

    #pragma unroll 1
    for (int t = 0; t < nt; ++t) {
      const int s0 = t * 64;
      const bool pf = (t + 1 < nt);
      // ---- T14: issue next tile's loads into registers (linear global) ----
      f16x8 ka[2], va[2];
      if (pf) {
        const int s1 = s0 + 64;
        #pragma unroll
        for (int q = 0; q < 2; ++q) {
          int idx = q * 512 + tid;
          int r = idx >> 4, g = idx & 15;
          ka[q] = *(const f16x8*)(Kg + (size_t)(s1 + r) * kvstride + g * 8);
        }
        #pragma unroll
        for (int q = 0; q < 2; ++q) {
          int idx = q * 512 + tid;
          int d = idx >> 3, g = idx & 7;
          va[q] = *(const f16x8*)(VTg + (size_t)d * T_SEQ + s1 + g * 8);
        }
      }
      // ---- S^T = K Q^T ----
      f32x4 sf[4] = {};
      __builtin_amdgcn_s_setprio(1);
      #pragma unroll
      for (int c = 0; c < 4; ++c) {
        #pragma unroll
        for (int nb = 0; nb < 4; ++nb) {
          f16x8 kf = *(const f16x8*)&Kl[(((nb * 16 + lr) * 16) + ((c * 4 + lg) ^ (lr & 7))) * 8];
          sf[nb] = __builtin_amdgcn_mfma_f32_16x16x32_f16(kf, qf[c], sf[nb], 0, 0, 0);
        }
      }
      __builtin_amdgcn_s_setprio(0);
      // ---- in-register softmax with defer-max (T13, THR=8) ----
      float v[16];
      #pragma unroll
      for (int nb = 0; nb < 4; ++nb)
        #pragma unroll
        for (int rr = 0; rr < 4; ++rr) {
          float x = sf[nb][rr] * sc;
          int kv = s0 + nb * 4 * 4 + nb * 0 + nb * 0;  // placeholder (overwritten below)
          kv = s0 + nb * 16 + lg * 4 + rr;
          v[nb * 4 + rr] = (kv > qrow) ? -1e30f : x;
        }
      float pm = v[0];
      #pragma unroll
      for (int i = 1; i < 16; ++i) pm = fmaxf(pm, v[i]);
      pm = fmaxf(pm, __shfl_xor(pm, 16));
      pm = fmaxf(pm, __shfl_xor(pm, 32));
      const bool nogrow = (__all(pm <= mi + 8.0f) != 0);
      const float mnew = nogrow ? mi : fmaxf(mi, pm);
      float rs = 0.f;
      #pragma unroll
      for (int i = 0; i < 16; ++i) { float p = __expf(v[i] - mnew); v[i] = p; rs += p; }
      rs += __shfl_xor(rs, 16);
      rs += __shfl_xor(rs, 32);
      if (nogrow) {
        li += rs;
      } else {
        float a = __expf(mi - mnew);
        mi = mnew;
        li = a * li + rs;
        float ab[4];
        #pragma unroll
        for (int rr = 0; rr < 4; ++rr) ab[rr] = __shfl(a, lg * 4 + rr);
        #pragma unroll
        for (int j = 0; j < 8; ++j)
          #pragma unroll
          for (int rr = 0; rr < 4; ++rr) o[j][rr] *= ab[rr];
      }
      // ---- PV in two ks-halves via per-wave P LDS ----
      #pragma unroll
      for (int ks = 0; ks < 2; ++ks) {
        #pragma unroll
        for (int nb2 = 0; nb2 < 2; ++nb2) {
          int nb = ks * 2 + nb2;
          f16x4 pk;
          #pragma unroll
          for (int rr = 0; rr < 4; ++rr) pk[rr] = (f16)v[nb * 4 + rr];
          *(f16x4*)&Pl[w][lr][nb2 * 16 + lg * 4] = pk;
        }
        f16x8 pa = *(const f16x8*)&Pl[w][lr][lg * 8];
        __builtin_amdgcn_s_setprio(1);
        #pragma unroll
        for (int j = 0; j < 8; ++j) {
          f16x8 vbj = *(const f16x8*)&Vl[(((j * 16 + lr) * 8) + ((ks * 4 + lg) ^ (lr & 7))) * 8];
          o[j] = __builtin_amdgcn_mfma_f32_16x16x32_f16(pa, vbj, o[j], 0, 0, 0);
        }
        __builtin_amdgcn_s_setprio(0);
      }
      __syncthreads();   // all waves done reading Kl/Vl tile t
      // ---- T14: write prefetched tile into LDS (swizzled dest) ----
      if (pf) {
        #pragma unroll
        for (int q = 0; q < 2; ++q) {
          int idx = q * 512 + tid;
          int r = idx >> 4, g = idx & 15;
          *(f16x8*)&Kl[(r * 16 + (g ^ (r & 7))) * 8] = ka[q];
        }
        #pragma unroll
        for (int q = 0; q < 2; ++q) {
          int idx = q * 512 + tid;
          int d = idx >> 3, g = idx & 7;
          *(f16x8*)&Vl[(d * 8 + (g ^ (d & 7))) * 8] = va[q];
        }
      }
      __syncthreads();   // writes visible before next compute
    }
    // ---- epilogue ----
    float lib[4];
    #pragma unroll
    for (int rr = 0; rr < 4; ++rr) lib[rr] = 1.f / __shfl(li, lg * 4 + rr);
    #pragma unroll
    for (int j = 0; j < 8; ++j)
      #pragma unroll
      for (int rr = 0; rr < 4; ++rr) {
        float vv = o[j][rr] * lib[rr];
        O[(size_t)(b * T_SEQ + qw + lg * 4 + rr) * (NQH * HD) + h * HD + j * 16 + lr] = (f16)vv;
      }
  }
}

// ---------------- differential combine: Z = attn_even - lam * attn_odd ------
__global__ void k_combine(const f16* __restrict__ attn, const float* __restrict__ lam,
                          f16* __restrict__ Z) {
  int idx = blockIdx.x * blockDim.x + threadIdx.x;
  int d4 = idx & 31;
  int tmp = idx >> 5;
  int h = tmp & 15;
  int row = tmp >> 4;
  if (row >= BATCH * T_SEQ) return;
  float lv = lam[row * 16 + h];
  f16x4 a1 = *(const f16x4*)(attn + (size_t)row * 4096 + (2 * h) * 128 + d4 * 4);
  f16x4 a2 = *(const f16x4*)(attn + (size_t)row * 4096 + (2 * h + 1) * 128 + d4 * 4);
  f16x4 z;
  #pragma unroll
  for (int e = 0; e < 4; ++e) z[e] = (f16)((float)a1[e] - lv * (float)a2[e]);
  *(f16x4*)(Z + (size_t)row * 2048 + h * 128 + d4 * 4) = z;
}

extern "C" void kernel_launch(void* const* d_in, const int* in_sizes, int n_in,
                              void* d_out, int out_size, void* d_ws, size_t ws_size,
                              hipStream_t stream) {
  const float* x    = (const float*)d_in[0];
  const float* cosb = (const float*)d_in[1];
  const float* sinb = (const float*)d_in[2];
  const float* Wq   = (const float*)d_in[3];
  const float* Wk   = (const float*)d_in[4];
  const float* Wv   = (const float*)d_in[5];
  const float* Wo   = (const float*)d_in[6];
  const float* Wlam = (const float*)d_in[7];

  char* ws = (char*)d_ws;
  f16*  xh     = (f16*)(ws);                      // 16 MB  x in f16
  f16*  WqkvT  = (f16*)(ws + 16777216);           // 32 MB  [Wq^T; Wk^T; Wv^T] (8192,2048)
  f16*  WoT    = (f16*)(ws + 50331648);           //  8 MB
  f16*  Qh     = (f16*)(ws + 58720256);           // 32 MB  (4096,4096) rope'd
  f16*  Kh     = (f16*)(ws + 92274688);           // 16 MB  (4096,2048) rope'd
  f16*  VTg    = (f16*)(ws + 109051904);          // 16 MB  (32 head-slices,128,2048)
  f16*  At     = (f16*)(ws + 125829120);          // 32 MB  attn out (4096,4096)
  f16*  Zh     = (f16*)(ws + 159383552);          // 16 MB  (4096,2048)
  float* lam   = (float*)(ws + 176160768);        // 256 KB (4096,16)

  k_transpose_all<<<dim3(128, 64, 4), 256, 0, stream>>>(Wq, Wk, Wv, Wo, WqkvT, WoT);
  k_lambda_conv<<<4096, 256, 0, stream>>>(x, Wlam, lam, xh);

  // fused QKV projection + RoPE + V-transpose: M=4096, N=8192, K=2048
  k_gemm2<256, 256, 2, 4, 3><<<512, 512, 0, stream>>>(xh, WqkvT, Qh, Kh, VTg,
                                                      cosb, sinb, 4096, 8192, 2048);

  k_attn5<<<512, 512, 0, stream>>>(Qh, Kh, VTg, At);

  k_combine<<<(BATCH * T_SEQ * 16 * 32) / 256, 256, 0, stream>>>(At, lam, Zh);

  // output projection: M=4096, N=2048, K=2048 -> f32 d_out
  k_gemm2<256, 128, 4, 2, 0><<<256, 512, 0, stream>>>(Zh, WoT, d_out, nullptr, nullptr,
                                                      nullptr, nullptr, 4096, 2048, 2048);
}

// Round 9
// 420.679 us; speedup vs baseline: 1.3597x; 1.0454x over previous
//
#include <hip/hip_runtime.h>

#define T_SEQ 2048
#define BATCH 2
#define DMODEL 2048
#define NQH 32
#define NKVH 16
#define HD 128

typedef _Float16 f16;
typedef _Float16 f16x8 __attribute__((ext_vector_type(8)));
typedef _Float16 f16x4 __attribute__((ext_vector_type(4)));
typedef _Float16 f16x2 __attribute__((ext_vector_type(2)));
typedef float f32x4 __attribute__((ext_vector_type(4)));

typedef const __attribute__((address_space(1))) void* gptr_t;
typedef __attribute__((address_space(3))) void* sptr_t;
#define GLDS16(g, l) __builtin_amdgcn_global_load_lds((gptr_t)(g), (sptr_t)(l), 16, 0, 0)

// ---------------- merged transpose+convert: all four W -> f16 transposed ----
__global__ __launch_bounds__(256) void k_transpose_all(const float* __restrict__ Wq,
                                                       const float* __restrict__ Wk,
                                                       const float* __restrict__ Wv,
                                                       const float* __restrict__ Wo,
                                                       f16* __restrict__ WqkvT,
                                                       f16* __restrict__ WoT) {
  __shared__ float tile[32][33];
  const int z = blockIdx.z;
  const float* W;
  f16* WT;
  int N;
  if (z == 0)      { W = Wq; WT = WqkvT;                          N = 4096; }
  else if (z == 1) { W = Wk; WT = WqkvT + (size_t)4096 * 2048;    N = 2048; }
  else if (z == 2) { W = Wv; WT = WqkvT + (size_t)6144 * 2048;    N = 2048; }
  else             { W = Wo; WT = WoT;                            N = 2048; }
  const int K = 2048;
  int n0 = blockIdx.x * 32;
  if (n0 >= N) return;
  int k0 = blockIdx.y * 32;
  int tx = threadIdx.x & 31;
  int ty0 = threadIdx.x >> 5;
  #pragma unroll
  for (int i = 0; i < 4; ++i) {
    int ty = ty0 + i * 8;
    tile[ty][tx] = W[(size_t)(k0 + ty) * N + n0 + tx];
  }
  __syncthreads();
  #pragma unroll
  for (int i = 0; i < 4; ++i) {
    int ty = ty0 + i * 8;
    WT[(size_t)(n0 + ty) * K + k0 + tx] = (f16)tile[tx][ty];
  }
}

// ---------------- pipelined GEMM (round-5 proven structure, THREADS param) ---
// C(M,N) = A(M,K) @ B(K,N), B given transposed (N,K). BK=64, double-buffered
// LDS, counted vmcnt (prefetch spans barriers), 2 barriers/tile.
// OM=0: f32 C.  OM=3: fused QKV epilogue (RoPE for Q/K, transposed store for V).
template<int BM, int BN, int WM, int WN, int THREADS, int OM>
__global__ __launch_bounds__(THREADS, 2) void k_gemm2(const f16* __restrict__ A,
                                                      const f16* __restrict__ BT,
                                                      void* __restrict__ C0,
                                                      f16* __restrict__ Kh,
                                                      f16* __restrict__ VTg,
                                                      const float* __restrict__ cosb,
                                                      const float* __restrict__ sinb,
                                                      int M, int N, int K) {
  constexpr int MR = BM / WM / 16;
  constexpr int NR = BN / WN / 16;
  constexpr int ACH = BM * 64 / 8 / THREADS;
  constexpr int BCH = BN * 64 / 8 / THREADS;
  static_assert(ACH + BCH == 8, "vmcnt constant assumes 8 loads/thread/stage");
  __shared__ alignas(16) f16 Al[2][BM * 64];
  __shared__ alignas(16) f16 Bl[2][BN * 64];
  const int tid = threadIdx.x;
  const int lane = tid & 63;
  const int w = tid >> 6;
  const int wr = w / WN, wc = w % WN;
  const int lr = lane & 15, lg = lane >> 4;
  const int nbx = N / BN;
  const int cpx = gridDim.x >> 3;
  const int wg = (blockIdx.x & 7) * cpx + (blockIdx.x >> 3);
  const int m0 = (wg / nbx) * BM, n0 = (wg % nbx) * BN;

  auto STAGE = [&](int buf, int kk) {
    #pragma unroll
    for (int q = 0; q < ACH; ++q) {
      int idx = q * THREADS + tid;
      int r = idx >> 3, g = idx & 7;
      GLDS16(A + (size_t)(m0 + r) * K + kk + ((g ^ (r & 7)) * 8), &Al[buf][idx * 8]);
    }
    #pragma unroll
    for (int q = 0; q < BCH; ++q) {
      int idx = q * THREADS + tid;
      int r = idx >> 3, g = idx & 7;
      GLDS16(BT + (size_t)(n0 + r) * K + kk + ((g ^ (r & 7)) * 8), &Bl[buf][idx * 8]);
    }
  };

  f32x4 acc[MR][NR] = {};
  STAGE(0, 0);
  const int nt = K / 64;
  #pragma unroll 2
  for (int t = 0; t < nt; ++t) {
    const int buf = t & 1;
    if (t + 1 < nt) {
      STAGE(buf ^ 1, (t + 1) * 64);
      __builtin_amdgcn_sched_barrier(0);
      asm volatile("s_waitcnt vmcnt(8)" ::: "memory");
    } else {
      __builtin_amdgcn_sched_barrier(0);
      asm volatile("s_waitcnt vmcnt(0)" ::: "memory");
    }
    __builtin_amdgcn_s_barrier();          // current tile visible to all waves
    __builtin_amdgcn_sched_barrier(0);
    #pragma unroll
    for (int kh = 0; kh < 2; ++kh) {
      f16x8 af[MR], bf[NR];
      #pragma unroll
      for (int i = 0; i < MR; ++i) {
        int r = wr * (BM / WM) + i * 16 + lr;
        af[i] = *(const f16x8*)&Al[buf][r * 64 + (((kh * 4 + lg) ^ (r & 7)) * 8)];
      }
      #pragma unroll
      for (int j = 0; j < NR; ++j) {
        int r = wc * (BN / WN) + j * 16 + lr;
        bf[j] = *(const f16x8*)&Bl[buf][r * 64 + (((kh * 4 + lg) ^ (r & 7)) * 8)];
      }
      #pragma unroll
      for (int i = 0; i < MR; ++i)
        #pragma unroll
        for (int j = 0; j < NR; ++j)
          acc[i][j] = __builtin_amdgcn_mfma_f32_16x16x32_f16(af[i], bf[j], acc[i][j], 0, 0, 0);
    }
    __builtin_amdgcn_sched_barrier(0);
    __builtin_amdgcn_s_barrier();          // all waves done reading buf
    __builtin_amdgcn_sched_barrier(0);
  }

  // ---- epilogue ----
  const int mb = m0 + wr * (BM / WM);
  const int nb = n0 + wc * (BN / WN);
  if constexpr (OM == 0) {
    float* C = (float*)C0;
    #pragma unroll
    for (int i = 0; i < MR; ++i)
      #pragma unroll
      for (int j = 0; j < NR; ++j) {
        int r0 = mb + i * 16 + lg * 4;
        int c = nb + j * 16 + lr;
        #pragma unroll
        for (int r = 0; r < 4; ++r)
          C[(size_t)(r0 + r) * N + c] = acc[i][j][r];
      }
  } else {
    if (n0 < 6144) {  // Q (cols 0..4095) or K (4096..6143): RoPE, row-major f16
      f16* dst = (n0 < 4096) ? (f16*)C0 : Kh;
      const int ncols = (n0 < 4096) ? 4096 : 2048;
      const int coff = (n0 < 4096) ? 0 : 4096;
      #pragma unroll
      for (int i = 0; i < MR; ++i)
        #pragma unroll
        for (int j = 0; j < NR; ++j) {
          int c = nb + j * 16 + lr - coff;
          int jp = (c & 127) >> 1;
          bool odd = (c & 1);
          #pragma unroll
          for (int r = 0; r < 4; ++r) {
            int row = mb + i * 16 + lg * 4 + r;
            int t = row & (T_SEQ - 1);
            float v = acc[i][j][r];
            float pv = __shfl_xor(v, 1);   // partner column (c^1) value
            float cs = cosb[t * 64 + jp], sn = sinb[t * 64 + jp];
            float out = odd ? (pv * sn + v * cs) : (v * cs - pv * sn);
            dst[(size_t)row * ncols + c] = (f16)out;
          }
        }
    } else {          // V (cols 6144..8191): transposed per head VT[b][h][d][t]
      #pragma unroll
      for (int i = 0; i < MR; ++i)
        #pragma unroll
        for (int j = 0; j < NR; ++j) {
          int c = nb + j * 16 + lr - 6144;
          int head = c >> 7, d = c & 127;
          int row0 = mb + i * 16 + lg * 4;
          int bb = row0 >> 11, t0 = row0 & (T_SEQ - 1);
          f16x4 zv;
          #pragma unroll
          for (int r = 0; r < 4; ++r) zv[r] = (f16)acc[i][j][r];
          *(f16x4*)(VTg + ((size_t)(bb * NKVH + head) * HD + d) * T_SEQ + t0) = zv;
        }
    }
  }
}

// ---------------- lambda = sigmoid(x @ Wlam) + x->f16 convert (fused) -------
__global__ __launch_bounds__(256) void k_lambda_conv(const float* __restrict__ x,
                                                     const float* __restrict__ Wlam,
                                                     float* __restrict__ lam,
                                                     f16* __restrict__ xh) {
  int row = blockIdx.x;
  const float* xr = x + (size_t)row * DMODEL;
  const int e = threadIdx.x * 8;
  const float4* xp = (const float4*)(xr + e);
  float4 a = xp[0], b2 = xp[1];
  float xv[8] = {a.x, a.y, a.z, a.w, b2.x, b2.y, b2.z, b2.w};
  f16x8 hv;
  #pragma unroll
  for (int j = 0; j < 8; ++j) hv[j] = (f16)xv[j];
  *(f16x8*)(xh + (size_t)row * DMODEL + e) = hv;
  float acc[16];
  #pragma unroll
  for (int h = 0; h < 16; ++h) acc[h] = 0.f;
  #pragma unroll
  for (int j = 0; j < 8; ++j) {
    const float4* wp = (const float4*)(Wlam + (size_t)(e + j) * 16);
    #pragma unroll
    for (int g = 0; g < 4; ++g) {
      float4 wv = wp[g];
      acc[g * 4 + 0] += xv[j] * wv.x; acc[g * 4 + 1] += xv[j] * wv.y;
      acc[g * 4 + 2] += xv[j] * wv.z; acc[g * 4 + 3] += xv[j] * wv.w;
    }
  }
  #pragma unroll
  for (int h = 0; h < 16; ++h)
    for (int off = 32; off > 0; off >>= 1)
      acc[h] += __shfl_down(acc[h], off);
  __shared__ float part[4][16];
  int lane = threadIdx.x & 63, w = threadIdx.x >> 6;
  if (lane == 0) {
    #pragma unroll
    for (int h = 0; h < 16; ++h) part[w][h] = acc[h];
  }
  __syncthreads();
  if (threadIdx.x < 16) {
    float s = part[0][threadIdx.x] + part[1][threadIdx.x] + part[2][threadIdx.x] + part[3][threadIdx.x];
    lam[row * 16 + threadIdx.x] = 1.f / (1.f + __expf(-s));
  }
}

// ---------------- causal flash attention v6: fused differential combine -----
// 512 threads (8 waves): waves 0-3 -> even head 2*hkv, waves 4-7 -> odd head.
// K/V staged ONCE per kv-head pair; T14 reg-prefetch of next tile; swapped
// QK^T in-register softmax + defer-max (T13). Epilogue: odd-head waves publish
// normalized O via LDS; even-head waves write Z = a1 - lam*a2 directly.
__global__ __launch_bounds__(512, 4) void k_attn6(const f16* __restrict__ Q,
                                                  const f16* __restrict__ K,
                                                  const f16* __restrict__ VT,
                                                  const float* __restrict__ lam,
                                                  f16* __restrict__ Z) {
  __shared__ f16 Kl[64 * 128];     // 16 KB, swizzled slots
  __shared__ f16 Vl[128 * 64];     // 16 KB, swizzled slots
  __shared__ f16 Pl[8][16][40];    // 10 KB, per-wave P half-tile
  __shared__ f16 Po[4][16][136];   // 17 KB, odd-head normalized outputs
  const int tid = threadIdx.x;
  const int lane = tid & 63;
  const int w = tid >> 6;          // 0..7
  const int lr = lane & 15, lg = lane >> 4;
  // ---- XCD-pinned decode: 512 blocks = 32 (b,hkv) groups x 16 qtile-pairs --
  const int flat = blockIdx.x;
  const int xcd = flat & 7;
  const int work = xcd * 64 + (flat >> 3);
  const int grp = work >> 4;           // b*16 + hkv
  const int bx = work & 15;
  const int b = grp >> 4, hkv = grp & 15;
  const int h = hkv * 2 + (w >> 2);    // wave's q-head
  const int wq = w & 3;                // wave's 16-row slice
  const int kvstride = NKVH * HD;
  const f16* Kg  = K  + (size_t)b * T_SEQ * kvstride + hkv * HD;
  const f16* VTg = VT + (size_t)(b * NKVH + hkv) * HD * T_SEQ;
  const float sc = 0.08838834764831845f;  // 1/sqrt(128)

  #pragma unroll 1
  for (int half = 0; half < 2; ++half) {
    const int qt = half ? (31 - bx) : bx;
    const int qb = qt * 64;
    const int qw = qb + wq * 16;
    const int qrow = qw + lr;
    f16x8 qf[4];
    {
      const f16* qp = Q + (size_t)(b * T_SEQ + qrow) * (NQH * HD) + h * HD + lg * 8;
      #pragma unroll
      for (int c = 0; c < 4; ++c) qf[c] = *(const f16x8*)(qp + c * 32);
    }
    f32x4 o[8] = {};
    float mi = -1e30f, li = 0.f;

    const int nt = qt + 1;
    // ---- blocking stage of tile 0 (GLDS direct, pre-swizzled source) ----
    #pragma unroll
    for (int q = 0; q < 2; ++q) {
      int idx = q * 512 + tid;
      int r = idx >> 4, g = idx & 15;
      GLDS16(Kg + (size_t)r * kvstride + (g ^ (r & 7)) * 8, &Kl[idx * 8]);
    }
    #pragma unroll
    for (int q = 0; q < 2; ++q) {
      int idx = q * 512 + tid;
      int d = idx >> 3, g = idx & 7;
      GLDS16(VTg + (size_t)d * T_SEQ + (g ^ (d & 7)) * 8, &Vl[idx * 8]);
    }
    __syncthreads();

    #pragma unroll 1
    for (int t = 0; t < nt; ++t) {
      const int s0 = t * 64;
      const bool pf = (t + 1 < nt);
      // ---- T14: issue next tile's loads into registers (linear global) ----
      f16x8 ka[2], va[2];
      if (pf) {
        const int s1 = s0 + 64;
        #pragma unroll
        for (int q = 0; q < 2; ++q) {
          int idx = q * 512 + tid;
          int r = idx >> 4, g = idx & 15;
          ka[q] = *(const f16x8*)(Kg + (size_t)(s1 + r) * kvstride + g * 8);
        }
        #pragma unroll
        for (int q = 0; q < 2; ++q) {
          int idx = q * 512 + tid;
          int d = idx >> 3, g = idx & 7;
          va[q] = *(const f16x8*)(VTg + (size_t)d * T_SEQ + s1 + g * 8);
        }
      }
      // ---- S^T = K Q^T ----
      f32x4 sf[4] = {};
      __builtin_amdgcn_s_setprio(1);
      #pragma unroll
      for (int c = 0; c < 4; ++c) {
        #pragma unroll
        for (int nb = 0; nb < 4; ++nb) {
          f16x8 kf = *(const f16x8*)&Kl[(((nb * 16 + lr) * 16) + ((c * 4 + lg) ^ (lr & 7))) * 8];
          sf[nb] = __builtin_amdgcn_mfma_f32_16x16x32_f16(kf, qf[c], sf[nb], 0, 0, 0);
        }
      }
      __builtin_amdgcn_s_setprio(0);
      // ---- in-register softmax with defer-max (T13, THR=8) ----
      float v[16];
      #pragma unroll
      for (int nb = 0; nb < 4; ++nb)
        #pragma unroll
        for (int rr = 0; rr < 4; ++rr) {
          float x = sf[nb][rr] * sc;
          int kv = s0 + nb * 16 + lg * 4 + rr;
          v[nb * 4 + rr] = (kv > qrow) ? -1e30f : x;
        }
      float pm = v[0];
      #pragma unroll
      for (int i = 1; i < 16; ++i) pm = fmaxf(pm, v[i]);
      pm = fmaxf(pm, __shfl_xor(pm, 16));
      pm = fmaxf(pm, __shfl_xor(pm, 32));
      const bool nogrow = (__all(pm <= mi + 8.0f) != 0);
      const float mnew = nogrow ? mi : fmaxf(mi, pm);
      float rs = 0.f;
      #pragma unroll
      for (int i = 0; i < 16; ++i) { float p = __expf(v[i] - mnew); v[i] = p; rs += p; }
      rs += __shfl_xor(rs, 16);
      rs += __shfl_xor(rs, 32);
      if (nogrow) {
        li += rs;
      } else {
        float a = __expf(mi - mnew);
        mi = mnew;
        li = a * li + rs;
        float ab[4];
        #pragma unroll
        for (int rr = 0; rr < 4; ++rr) ab[rr] = __shfl(a, lg * 4 + rr);
        #pragma unroll
        for (int j = 0; j < 8; ++j)
          #pragma unroll
          for (int rr = 0; rr < 4; ++rr) o[j][rr] *= ab[rr];
      }
      // ---- PV in two ks-halves via per-wave P LDS ----
      #pragma unroll
      for (int ks = 0; ks < 2; ++ks) {
        #pragma unroll
        for (int nb2 = 0; nb2 < 2; ++nb2) {
          int nb = ks * 2 + nb2;
          f16x4 pk;
          #pragma unroll
          for (int rr = 0; rr < 4; ++rr) pk[rr] = (f16)v[nb * 4 + rr];
          *(f16x4*)&Pl[w][lr][nb2 * 16 + lg * 4] = pk;
        }
        f16x8 pa = *(const f16x8*)&Pl[w][lr][lg * 8];
        __builtin_amdgcn_s_setprio(1);
        #pragma unroll
        for (int j = 0; j < 8; ++j) {
          f16x8 vbj = *(const f16x8*)&Vl[(((j * 16 + lr) * 8) + ((ks * 4 + lg) ^ (lr & 7))) * 8];
          o[j] = __builtin_amdgcn_mfma_f32_16x16x32_f16(pa, vbj, o[j], 0, 0, 0);
        }
        __builtin_amdgcn_s_setprio(0);
      }
      __syncthreads();   // all waves done reading Kl/Vl tile t
      // ---- T14: write prefetched tile into LDS (swizzled dest) ----
      if (pf) {
        #pragma unroll
        for (int q = 0; q < 2; ++q) {
          int idx = q * 512 + tid;
          int r = idx >> 4, g = idx & 15;
          *(f16x8*)&Kl[(r * 16 + (g ^ (r & 7))) * 8] = ka[q];
        }
        #pragma unroll
        for (int q = 0; q < 2; ++q) {
          int idx = q * 512 + tid;
          int d = idx >> 3, g = idx & 7;
          *(f16x8*)&Vl[(d * 8 + (g ^ (d & 7))) * 8] = va[q];
        }
      }
      __syncthreads();   // writes visible before next compute
    }
    // ---- epilogue with fused differential combine ----
    float lib[4];
    #pragma unroll
    for (int rr = 0; rr < 4; ++rr) lib[rr] = 1.f / __shfl(li, lg * 4 + rr);
    if (w >= 4) {        // odd head: publish normalized output
      #pragma unroll
      for (int j = 0; j < 8; ++j)
        #pragma unroll
        for (int rr = 0; rr < 4; ++rr)
          Po[wq][lg * 4 + rr][j * 16 + lr] = (f16)(o[j][rr] * lib[rr]);
    }
    __syncthreads();
    if (w < 4) {         // even head: combine and store
      float lamv[4];
      #pragma unroll
      for (int rr = 0; rr < 4; ++rr)
        lamv[rr] = lam[(size_t)(b * T_SEQ + qw + lg * 4 + rr) * 16 + hkv];
      #pragma unroll
      for (int j = 0; j < 8; ++j)
        #pragma unroll
        for (int rr = 0; rr < 4; ++rr) {
          float a1 = o[j][rr] * lib[rr];
          float a2 = (float)Po[wq][lg * 4 + rr][j * 16 + lr];
          Z[(size_t)(b * T_SEQ + qw + lg * 4 + rr) * 2048 + hkv * 128 + j * 16 + lr] =
              (f16)(a1 - lamv[rr] * a2);
        }
    }
    __syncthreads();     // Po free before next half
  }
}

extern "C" void kernel_launch(void* const* d_in, const int* in_sizes, int n_in,
                              void* d_out, int out_size, void* d_ws, size_t ws_size,
                              hipStream_t stream) {
  const float* x    = (const float*)d_in[0];
  const float* cosb = (const float*)d_in[1];
  const float* sinb = (const float*)d_in[2];
  const float* Wq   = (const float*)d_in[3];
  const float* Wk   = (const float*)d_in[4];
  const float* Wv   = (const float*)d_in[5];
  const float* Wo   = (const float*)d_in[6];
  const float* Wlam = (const float*)d_in[7];

  char* ws = (char*)d_ws;
  f16*  xh     = (f16*)(ws);                      // 16 MB  x in f16
  f16*  WqkvT  = (f16*)(ws + 16777216);           // 32 MB  [Wq^T; Wk^T; Wv^T] (8192,2048)
  f16*  WoT    = (f16*)(ws + 50331648);           //  8 MB
  f16*  Qh     = (f16*)(ws + 58720256);           // 32 MB  (4096,4096) rope'd
  f16*  Kh     = (f16*)(ws + 92274688);           // 16 MB  (4096,2048) rope'd
  f16*  VTg    = (f16*)(ws + 109051904);          // 16 MB  (32 head-slices,128,2048)
  f16*  Zh     = (f16*)(ws + 159383552);          // 16 MB  (4096,2048) combined
  float* lam   = (float*)(ws + 176160768);        // 256 KB (4096,16)

  k_transpose_all<<<dim3(128, 64, 4), 256, 0, stream>>>(Wq, Wk, Wv, Wo, WqkvT, WoT);
  k_lambda_conv<<<4096, 256, 0, stream>>>(x, Wlam, lam, xh);

  // fused QKV projection + RoPE + V-transpose: M=4096, N=8192, K=2048
  k_gemm2<256, 256, 2, 4, 512, 3><<<512, 512, 0, stream>>>(xh, WqkvT, Qh, Kh, VTg,
                                                           cosb, sinb, 4096, 8192, 2048);

  // attention + fused differential combine -> Zh
  k_attn6<<<512, 512, 0, stream>>>(Qh, Kh, VTg, lam, Zh);

  // output projection: M=4096, N=2048, K=2048 -> f32 d_out (128^2 tile, 2 blk/CU)
  k_gemm2<128, 128, 2, 2, 256, 0><<<512, 256, 0, stream>>>(Zh, WoT, d_out, nullptr, nullptr,
                                                           nullptr, nullptr, 4096, 2048, 2048);
}